// Round 10
// baseline (84.258 us; speedup 1.0000x reference)
//
#include <hip/hip_runtime.h>

// GraphAdjacencyLayer: W[i][j] = thresh((fn_i . fn_j)^2), fn = row-normalized features.
// N x 128 fp32 in, N x N fp32 out (N=8192). 256 MB output.
//
// R10: best-known fused structure (R2/R3: norm->bf16 ws, then Gram MFMA + threshold +
// direct float4 stores) with ONE new variable: bijective XCD-aware block swizzle so
// each XCD owns a contiguous 32 MB row-band of the output (8 row-bands = 512 blocks
// per XCD), making each XCD's L2 write-back stream sequential instead of scattered.
// Everything else is unchanged from the 79.3 us configuration.
//
// Evidence so far: writes of 256 MB from any shader structure = ~75 us (~3.4 TB/s
// steady-state rewrite of a hot buffer); compute fully hides under the write stream.

typedef __bf16 bf16x8 __attribute__((ext_vector_type(8)));
typedef float f32x4 __attribute__((ext_vector_type(4)));

// ---------------- K1: row-normalize fp32 -> bf16 ----------------------------
__global__ __launch_bounds__(256)
void norm_cvt_kernel(const float* __restrict__ F, unsigned short* __restrict__ Fb, int N)
{
    const int gtid = blockIdx.x * 256 + threadIdx.x;
    const int row  = gtid >> 5;
    const int c    = gtid & 31;          // float4 column
    if (row >= N) return;

    float4 v = ((const float4*)F)[(size_t)row * 32 + c];
    float ss = v.x * v.x + v.y * v.y + v.z * v.z + v.w * v.w;
    #pragma unroll
    for (int m = 1; m <= 16; m <<= 1) ss += __shfl_xor(ss, m, 64);   // within 32-group
    const float s = 1.0f / (sqrtf(ss) + 1e-12f);

    ushort4 u;
    u.x = __builtin_bit_cast(unsigned short, (__bf16)(v.x * s));
    u.y = __builtin_bit_cast(unsigned short, (__bf16)(v.y * s));
    u.z = __builtin_bit_cast(unsigned short, (__bf16)(v.z * s));
    u.w = __builtin_bit_cast(unsigned short, (__bf16)(v.w * s));
    ((ushort4*)Fb)[(size_t)row * 32 + c] = u;
}

// ---------------- K2: Gram + threshold, float4 stores, XCD row-band swizzle --
// 128x128 tile per 256-thread block (4 waves, 2x2 of 64x64). K=128, no K-loop.
// Swapped mfma(b,a): lane (fr=lane&15, fkq=lane>>4) holds output row fr,
// cols fkq*4+0..3 (consecutive) per fragment -> one float4 store per fragment.
__global__ __launch_bounds__(256, 3)
void gram_thresh_kernel(const unsigned short* __restrict__ Fb, float* __restrict__ out, int N)
{
    const int tid  = threadIdx.x;
    const int lane = tid & 63;
    const int wid  = tid >> 6;
    const int wm   = wid >> 1;
    const int wn   = wid & 1;
    const int fr   = lane & 15;          // fragment row index
    const int fkq  = lane >> 4;          // col quad 0..3

    // XCD-aware bijective swizzle: grid = 4096 flat blocks, 8 XCDs round-robin.
    // XCD k gets lbid in [k*512, (k+1)*512) -> row bands [8k, 8k+8) -> rows
    // [1024k, 1024(k+1)): a contiguous 32 MB output region per XCD.
    const int bid  = blockIdx.x;
    const int lbid = (bid & 7) * 512 + (bid >> 3);
    const int rowTile = (lbid >> 6) * 128;   // 64 col-tiles per row band
    const int colTile = (lbid & 63) * 128;

    const bf16x8* __restrict__ base = (const bf16x8*)Fb;   // row stride = 16 chunks
    const int rowA0 = rowTile + wm * 64 + fr;
    const int rowB0 = colTile + wn * 64 + fr;

    // preload all B fragments (output-column rows): 16 loads, 64 VGPR
    bf16x8 b[4][4];
    #pragma unroll
    for (int n = 0; n < 4; ++n)
        #pragma unroll
        for (int ks = 0; ks < 4; ++ks)
            b[n][ks] = base[(size_t)(rowB0 + n * 16) * 16 + ks * 4 + fkq];

    const float c1 = 0.9486832980505138f;  // sqrt(0.9)
    const float c2 = 0.7071067811865476f;  // sqrt(0.5)
    const bool diagBlock = (rowTile == colTile);

    #pragma unroll
    for (int m = 0; m < 4; ++m) {
        bf16x8 a[4];
        #pragma unroll
        for (int ks = 0; ks < 4; ++ks)
            a[ks] = base[(size_t)(rowA0 + m * 16) * 16 + ks * 4 + fkq];

        f32x4 acc[4];
        #pragma unroll
        for (int n = 0; n < 4; ++n) acc[n] = (f32x4){0.f, 0.f, 0.f, 0.f};

        #pragma unroll
        for (int ks = 0; ks < 4; ++ks)
            #pragma unroll
            for (int n = 0; n < 4; ++n)
                acc[n] = __builtin_amdgcn_mfma_f32_16x16x32_bf16(b[n][ks], a[ks], acc[n], 0, 0, 0);

        const int grow = rowTile + wm * 64 + m * 16 + fr;
        float* __restrict__ orow = out + (size_t)grow * N;

        #pragma unroll
        for (int n = 0; n < 4; ++n) {
            const int c0 = colTile + wn * 64 + n * 16 + fkq * 4;
            f32x4 wv;
            #pragma unroll
            for (int j = 0; j < 4; ++j) {
                const float g = fabsf(acc[n][j]);
                wv[j] = g >= c1 ? 1.0f : (g >= c2 ? 0.5f : 0.0f);
            }
            if (diagBlock) {
                const int d = grow - c0;        // component hit if 0..3
                if (d >= 0 && d < 4) wv[d] = 0.0f;
            }
            *(f32x4*)(orow + c0) = wv;
        }
    }
}

extern "C" void kernel_launch(void* const* d_in, const int* in_sizes, int n_in,
                              void* d_out, int out_size, void* d_ws, size_t ws_size,
                              hipStream_t stream) {
    const float* features = (const float*)d_in[0];
    float* out = (float*)d_out;
    const int D = 128;
    const int N = in_sizes[0] / D;   // 8192

    unsigned short* Fb = (unsigned short*)d_ws;
    const int k1_blocks = (N * 32 + 255) / 256;
    norm_cvt_kernel<<<k1_blocks, 256, 0, stream>>>(features, Fb, N);

    const int nblk = (N / 128) * (N / 128);   // 4096 flat
    gram_thresh_kernel<<<nblk, 256, 0, stream>>>(Fb, out, N);
}